// Round 8
// baseline (82.253 us; speedup 1.0000x reference)
//
#include <hip/hip_runtime.h>
#include <math.h>

// Problem constants (B=8, P=64, V=32, N_TH1=30 -> D=1626)
#define NBP 512          // B*P
#define VV 32
#define DD 1626
#define DSPAN 407        // dirs per block (4 blocks along dir dim)

// Output layout (flat float32, concatenated in return order)
#define O_POINTS 0                         // (8,64*1626,3)  = 2497536
#define O_DIRH   2497536                   // (8,64,1626,4)  = 3330048
#define O_OVER   5827584                   // (8,64,1)       = 512
#define O_RETR   5828096                   // (8,64,1)       = 512
#define O_MEAN   5828608                   // (8,64,3)       = 1536
#define O_LOCAL  5830144                   // (8,64,32,3)    = 49152

#define L10_2 0.3010299956639812f    // log10(2)
#define L2_10 3.321928094887362f     // log2(10)
#define LH_MIN -66.43856189774725f   // log2(1e-20)

__device__ __forceinline__ float fexp2(float x) {
  return __builtin_amdgcn_exp2f(x);    // raw v_exp_f32
}

__device__ __forceinline__ void make_dir(int d, float& x, float& y, float& z) {
  if (d < 1624) {
    int i1 = d / 58;
    int i2 = d - i1 * 58;
    i1 += 1;
    const float STEP = 0.10833078115826873f;   // pi/29
    float th1 = -1.5707963267948966f + (float)i1 * STEP;
    float th2 = -3.14159265358979323846f + (float)i2 * STEP;
    float s1, c1, s2, c2;
    sincosf(th1, &s1, &c1);
    sincosf(th2, &s2, &c2);
    x = c1 * c2; y = c1 * s2; z = s1;
  } else if (d == 1624) {
    x = -6.123234e-17f; y = -7.49880e-33f; z = -1.0f;
  } else {
    x = -6.123234e-17f; y = -7.49880e-33f; z = 1.0f;
  }
}

__global__ __launch_bounds__(256) void dirs_kernel(float4* __restrict__ gdirs) {
  int d = blockIdx.x * 256 + threadIdx.x;
  if (d >= DD) return;
  float x, y, z;
  make_dir(d, x, y, z);
  gdirs[d] = make_float4(x, y, z, 0.f);
}

// 4 lanes cooperate on one direction; each lane owns 8 vertices in registers.
// No LDS, no __syncthreads; all reductions are quad __shfl_xor (DPP).
__global__ __launch_bounds__(256) void spt_kernel(
    const float* __restrict__ vertices,
    const float* __restrict__ smooth,
    const float4* __restrict__ gdirs,
    float* __restrict__ out)
{
  const int bp   = blockIdx.x;    // 0..511
  const int bz   = blockIdx.y;    // 0..3
  const int tid  = threadIdx.x;
  const int lane = tid & 3;       // vertex-octet owner within quad
  const int grp  = tid >> 2;      // direction slot 0..63

  const int dbase = bz * DSPAN;
  const int dend  = (DD - dbase) < DSPAN ? (DD - dbase) : DSPAN;  // 407/405

  // ---- load this lane's 8 vertices (24 contiguous floats, 16B aligned) ----
  const float4* vp4 = (const float4*)(vertices + bp * (VV * 3) + lane * 24);
  float t[24];
  {
    float4 q;
    q = vp4[0]; t[0]=q.x;  t[1]=q.y;  t[2]=q.z;  t[3]=q.w;
    q = vp4[1]; t[4]=q.x;  t[5]=q.y;  t[6]=q.z;  t[7]=q.w;
    q = vp4[2]; t[8]=q.x;  t[9]=q.y;  t[10]=q.z; t[11]=q.w;
    q = vp4[3]; t[12]=q.x; t[13]=q.y; t[14]=q.z; t[15]=q.w;
    q = vp4[4]; t[16]=q.x; t[17]=q.y; t[18]=q.z; t[19]=q.w;
    q = vp4[5]; t[20]=q.x; t[21]=q.y; t[22]=q.z; t[23]=q.w;
  }

  // ---- mean over 32 vertices: lane-local 8, then quad shfl_xor reduce ----
  float sx = 0.f, sy = 0.f, sz = 0.f;
#pragma unroll
  for (int i = 0; i < 8; i++) { sx += t[3*i]; sy += t[3*i+1]; sz += t[3*i+2]; }
  sx += __shfl_xor(sx, 1); sy += __shfl_xor(sy, 1); sz += __shfl_xor(sz, 1);
  sx += __shfl_xor(sx, 2); sy += __shfl_xor(sy, 2); sz += __shfl_xor(sz, 2);
  const float mx = sx * (1.0f/32.0f);
  const float my = sy * (1.0f/32.0f);
  const float mz = sz * (1.0f/32.0f);

  float lvx[8], lvy[8], lvz[8];
#pragma unroll
  for (int i = 0; i < 8; i++) {
    lvx[i] = t[3*i]   - mx;
    lvy[i] = t[3*i+1] - my;
    lvz[i] = t[3*i+2] - mz;
  }

  // ---- side outputs (once, by bz==0, quad 0) ----
  if (bz == 0 && tid < 4) {
    float* lp = out + O_LOCAL + bp * (VV * 3) + lane * 24;
#pragma unroll
    for (int i = 0; i < 8; i++) {
      lp[3*i] = lvx[i]; lp[3*i+1] = lvy[i]; lp[3*i+2] = lvz[i];
    }
    if (lane == 0) {
      out[O_MEAN + bp*3 + 0] = mx;
      out[O_MEAN + bp*3 + 1] = my;
      out[O_MEAN + bp*3 + 2] = mz;
      out[O_OVER + bp] = 0.f;
      out[O_RETR + bp] = 0.f;
    }
  }

  const float p     = smooth[bp];
  const float inv_p = 1.0f / p;
  const float pm1   = p - 1.0f;
  const float plt   = p * L10_2;

  for (int it = 0; it < 7; ++it) {
    const int  idx    = it * 64 + grp;
    const bool active = idx < dend;
    const int  d      = dbase + (active ? idx : 0);
    float4 dv = gdirs[d];
    const float dx = dv.x, dy = dv.y, dz = dv.z;

    // pass 1: l[i] = log2(relu(lv.dir)); quad-max
    float l[8];
#pragma unroll
    for (int i = 0; i < 8; i++) {
      float zv = fmaxf(fmaf(lvx[i], dx, fmaf(lvy[i], dy, lvz[i]*dz)), 0.f);
      l[i] = __log2f(zv);                  // log2(0) = -inf
    }
    float lmax = fmaxf(fmaxf(fmaxf(l[0],l[1]), fmaxf(l[2],l[3])),
                       fmaxf(fmaxf(l[4],l[5]), fmaxf(l[6],l[7])));
    lmax = fmaxf(lmax, __shfl_xor(lmax, 1));
    lmax = fmaxf(lmax, __shfl_xor(lmax, 2));

    // rescale exponent kc (lmax=-inf -> kc=20); group-uniform by construction
    const float expo = lmax * plt;
    float kc = 0.f;
    if (expo < -20.f) {
      kc = fminf(fmaxf(ceilf((-15.f - expo) * inv_p), 0.f), 20.f);
    }
    const float kcl = kc * L2_10;
    const float pkc = p * kcl;

    // pass 2: ssum = sum 2^(p*l + p*kcl) ; quad-reduce
    float e[8];
#pragma unroll
    for (int i = 0; i < 8; i++) e[i] = fexp2(fmaf(p, l[i], pkc));
    float ss = ((e[0]+e[1]) + (e[2]+e[3])) + ((e[4]+e[5]) + (e[6]+e[7]));
    ss += __shfl_xor(ss, 1);
    ss += __shfl_xor(ss, 2);

    float lh = LH_MIN;
    if (ss > 0.f) lh = inv_p * __log2f(ss);
    const float c3 = pm1 * (kcl - lh);

    // pass 3: dhdz = 2^((p-1)*l + c3); partial dhdx, quad-reduce
    float ax0=0.f, ax1=0.f, ay0=0.f, ay1=0.f, az0=0.f, az1=0.f;
#pragma unroll
    for (int i = 0; i < 8; i += 2) {
      float d0 = fexp2(fmaf(pm1, l[i],   c3));
      float d1 = fexp2(fmaf(pm1, l[i+1], c3));
      ax0 = fmaf(d0, lvx[i],   ax0);  ax1 = fmaf(d1, lvx[i+1], ax1);
      ay0 = fmaf(d0, lvy[i],   ay0);  ay1 = fmaf(d1, lvy[i+1], ay1);
      az0 = fmaf(d0, lvz[i],   az0);  az1 = fmaf(d1, lvz[i+1], az1);
    }
    float ax = ax0 + ax1, ay = ay0 + ay1, az = az0 + az1;
    ax += __shfl_xor(ax, 1); ay += __shfl_xor(ay, 1); az += __shfl_xor(az, 1);
    ax += __shfl_xor(ax, 2); ay += __shfl_xor(ay, 2); az += __shfl_xor(az, 2);

    if (active) {
      const int pbase = bp * DD + d;
      if (lane < 3) {
        // lanes 0..2 of each quad write one point component -> contiguous
        const float val = (lane == 0) ? ax + mx : ((lane == 1) ? ay + my : az + mz);
        out[O_POINTS + pbase*3 + lane] = val;
      } else {
        // lane 3 writes the float4 direction_h row
        dv.w = fexp2(lh - kcl);            // h / k
        ((float4*)(out + O_DIRH))[pbase] = dv;
      }
    }
  }
}

extern "C" void kernel_launch(void* const* d_in, const int* in_sizes, int n_in,
                              void* d_out, int out_size, void* d_ws, size_t ws_size,
                              hipStream_t stream) {
  const float* vertices = (const float*)d_in[0];  // (8,64,32,3) f32
  const float* smooth   = (const float*)d_in[1];  // (8,64) f32
  float* out = (float*)d_out;
  float4* gdirs = (float4*)d_ws;                  // DD float4s (26 KB)

  dirs_kernel<<<dim3((DD + 255) / 256), 256, 0, stream>>>(gdirs);
  spt_kernel<<<dim3(NBP, 4), 256, 0, stream>>>(vertices, smooth, gdirs, out);
}